// Round 5
// baseline (504.016 us; speedup 1.0000x reference)
//
#include <hip/hip_runtime.h>
#include <hip/hip_fp16.h>
#include <math.h>

#define N_NODES 50000
#define N_EDGES 800000
#define DIM 128
#define NHEADS 8
#define LN_EPS 1e-5f
#define LEAKY 0.2f
#define NPB 16     // nodes per block for k_node_va
#define OPB 32     // nodes per block for k_out_ln
#define NSB 196    // ceil(N_NODES/256) scan blocks

// ---------------- pack/unpack (P, deter) as half2 in one int ----------------
__device__ __forceinline__ int pack_pd(float p, float dt) {
    __half2 h = __floats2half2_rn(p, dt);
    int r; __builtin_memcpy(&r, &h, 4); return r;
}
__device__ __forceinline__ float2 unpack_pd(int v) {
    __half2 h; __builtin_memcpy(&h, &v, 4);
    return __half22float2(h);   // .x = P, .y = deter
}

// ---------------- K1: U1 = W4@W1, U2 = W4@W2, c = W4@W3 (tiny) --------------
__global__ __launch_bounds__(128) void k_prep(
    const float* __restrict__ W1, const float* __restrict__ W2,
    const float* __restrict__ W3, const float* __restrict__ W4,
    float* __restrict__ U1, float* __restrict__ U2, float* __restrict__ c) {
    int h = blockIdx.x;       // 0..7
    int k = threadIdx.x;      // 0..127
    float a1 = 0.f, a2 = 0.f;
    for (int d = 0; d < DIM; ++d) {
        float w4 = W4[h * DIM + d];
        a1 += w4 * W1[d * DIM + k];
        a2 += w4 * W2[d * DIM + k];
    }
    U1[h * DIM + k] = a1;
    U2[h * DIM + k] = a2;
    __shared__ float red[DIM];
    red[k] = W4[h * DIM + k] * W3[k];
    __syncthreads();
    if (k == 0) {
        float s = 0.f;
        for (int i = 0; i < DIM; ++i) s += red[i];
        c[h] = s;
    }
}

// ------- K2: Vh = fp16(H@Wv^T) ; A1 = H@U1^T ; A2 = H@U2^T ------------------
__global__ __launch_bounds__(128) void k_node_va(
    const float* __restrict__ H, const float* __restrict__ Wv,
    const float* __restrict__ U1, const float* __restrict__ U2,
    __half* __restrict__ Vh, float* __restrict__ A1, float* __restrict__ A2) {
    __shared__ __align__(16) float Hs[NPB][DIM + 4];
    __shared__ float Us1[NHEADS * 130];
    __shared__ float Us2[NHEADS * 130];
    int d = threadIdx.x;
    int n0 = blockIdx.x * NPB;
    #pragma unroll
    for (int i = 0; i < NPB; ++i) Hs[i][d] = H[(size_t)(n0 + i) * DIM + d];
    #pragma unroll
    for (int r = 0; r < NHEADS; ++r) {
        Us1[r * 130 + d] = U1[r * DIM + d];
        Us2[r * 130 + d] = U2[r * DIM + d];
    }
    __syncthreads();
    float accv[NPB];
    #pragma unroll
    for (int i = 0; i < NPB; ++i) accv[i] = 0.f;
    const float4* Wv4 = reinterpret_cast<const float4*>(Wv + (size_t)d * DIM);
    #pragma unroll 4
    for (int k4 = 0; k4 < DIM / 4; ++k4) {
        float4 wv = Wv4[k4];
        #pragma unroll
        for (int i = 0; i < NPB; ++i) {
            float4 hh = *reinterpret_cast<const float4*>(&Hs[i][k4 * 4]);
            accv[i] += hh.x * wv.x + hh.y * wv.y + hh.z * wv.z + hh.w * wv.w;
        }
    }
    #pragma unroll
    for (int i = 0; i < NPB; ++i)
        Vh[(size_t)(n0 + i) * DIM + d] = __float2half_rn(accv[i]);
    int i = d >> 3, h = d & 7;
    float a1 = 0.f, a2 = 0.f;
    for (int k = 0; k < DIM; ++k) {
        float hv = Hs[i][k];
        a1 += hv * Us1[h * 130 + k];
        a2 += hv * Us2[h * 130 + k];
    }
    A1[(size_t)(n0 + i) * NHEADS + h] = a1;   // coalesced: A1[n0*8 + d]
    A2[(size_t)(n0 + i) * NHEADS + h] = a2;
}

// ---------------- K3: degree histogram --------------------------------------
__global__ __launch_bounds__(256) void k_hist(
    const int* __restrict__ ei, int* __restrict__ deg) {
    int e = blockIdx.x * 256 + threadIdx.x;
    if (e < N_EDGES) atomicAdd(&deg[ei[N_EDGES + e]], 1);
}

// ---------------- K4a: per-block partial sums of deg ------------------------
__global__ __launch_bounds__(256) void k_scan1(
    const int* __restrict__ deg, int* __restrict__ partial) {
    int t = threadIdx.x;
    int idx = blockIdx.x * 256 + t;
    int v = (idx < N_NODES) ? deg[idx] : 0;
    #pragma unroll
    for (int off = 32; off > 0; off >>= 1) v += __shfl_down(v, off, 64);
    __shared__ int ws_[4];
    if ((t & 63) == 0) ws_[t >> 6] = v;
    __syncthreads();
    if (t == 0) partial[blockIdx.x] = ws_[0] + ws_[1] + ws_[2] + ws_[3];
}

// -------- K4b: per-block local scan; each block also scans the partials -----
__global__ __launch_bounds__(256) void k_scan3(
    const int* __restrict__ deg, const int* __restrict__ partial,
    int* __restrict__ row_off, int* __restrict__ cursor) {
    __shared__ int shp[256];
    __shared__ int sh[256];
    int t = threadIdx.x;
    int pv = (t < NSB) ? partial[t] : 0;
    shp[t] = pv;
    int idx = blockIdx.x * 256 + t;
    int v = (idx < N_NODES) ? deg[idx] : 0;
    sh[t] = v;
    __syncthreads();
    #pragma unroll
    for (int off = 1; off < 256; off <<= 1) {
        int u1 = (t >= off) ? shp[t - off] : 0;
        int u2 = (t >= off) ? sh[t - off] : 0;
        __syncthreads();
        shp[t] += u1;
        sh[t] += u2;
        __syncthreads();
    }
    int pofs = (blockIdx.x == 0) ? 0 : shp[blockIdx.x - 1];
    int excl = sh[t] - v + pofs;
    if (idx < N_NODES) {
        row_off[idx] = excl;
        cursor[idx] = excl;
    }
    if (idx == N_NODES - 1) row_off[N_NODES] = excl + v;   // == N_EDGES
}

// ---------------- K5: bucket edges by dst; record = (src, half2(P,deter)) ---
__global__ __launch_bounds__(256) void k_bucket(
    const int* __restrict__ ei, const float* __restrict__ P,
    const float* __restrict__ deter, int* __restrict__ cursor,
    int2* __restrict__ rec) {
    int e = blockIdx.x * 256 + threadIdx.x;
    if (e >= N_EDGES) return;
    int src = ei[e];
    int dst = ei[N_EDGES + e];
    int pos = atomicAdd(&cursor[dst], 1);
    rec[pos] = make_int2(src, pack_pd(P[e], deter[e]));
}

// ---------------- K6: fused softmax + aggregation (4x unrolled) -------------
// wave per node; lane d owns dims (2d, 2d+1) -> head h = d>>3
__global__ __launch_bounds__(256) void k_sm_agg(
    const int* __restrict__ row_off, const int2* __restrict__ rec,
    const float* __restrict__ A1, const float* __restrict__ A2,
    const float* __restrict__ cvec, const __half2* __restrict__ Vh2,
    float2* __restrict__ agg2) {
    int n = (blockIdx.x * 256 + threadIdx.x) >> 6;
    int d = threadIdx.x & 63;
    if (n >= N_NODES) return;
    int h = d >> 3;
    float a1 = A1[(size_t)n * NHEADS + h];
    float ch = cvec[h];
    int start = row_off[n], end = row_off[n + 1];
    float s = 0.f, accx = 0.f, accy = 0.f;
    int j = start;
    for (; j + 4 <= end; j += 4) {
        int2 r0 = rec[j], r1 = rec[j + 1], r2 = rec[j + 2], r3 = rec[j + 3];
        int s0 = r0.x, s1 = r1.x, s2 = r2.x, s3 = r3.x;
        float a20 = A2[(size_t)s0 * NHEADS + h];
        float a21 = A2[(size_t)s1 * NHEADS + h];
        float a22 = A2[(size_t)s2 * NHEADS + h];
        float a23 = A2[(size_t)s3 * NHEADS + h];
        __half2 v0 = Vh2[(size_t)s0 * (DIM / 2) + d];
        __half2 v1 = Vh2[(size_t)s1 * (DIM / 2) + d];
        __half2 v2 = Vh2[(size_t)s2 * (DIM / 2) + d];
        __half2 v3 = Vh2[(size_t)s3 * (DIM / 2) + d];
        float2 p0 = unpack_pd(r0.y), p1 = unpack_pd(r1.y);
        float2 p2 = unpack_pd(r2.y), p3 = unpack_pd(r3.y);
        float l0 = a1 + a20 + p0.x * ch + p0.y;
        float l1 = a1 + a21 + p1.x * ch + p1.y;
        float l2 = a1 + a22 + p2.x * ch + p2.y;
        float l3 = a1 + a23 + p3.x * ch + p3.y;
        l0 = (l0 >= 0.f) ? l0 : LEAKY * l0;
        l1 = (l1 >= 0.f) ? l1 : LEAKY * l1;
        l2 = (l2 >= 0.f) ? l2 : LEAKY * l2;
        l3 = (l3 >= 0.f) ? l3 : LEAKY * l3;
        float e0 = __expf(l0), e1 = __expf(l1), e2 = __expf(l2), e3 = __expf(l3);
        s += e0 + e1 + e2 + e3;
        float2 f0 = __half22float2(v0), f1 = __half22float2(v1);
        float2 f2 = __half22float2(v2), f3 = __half22float2(v3);
        accx += e0 * f0.x + e1 * f1.x + e2 * f2.x + e3 * f3.x;
        accy += e0 * f0.y + e1 * f1.y + e2 * f2.y + e3 * f3.y;
    }
    for (; j < end; ++j) {
        int2 r = rec[j];
        int src = r.x;
        float2 pd = unpack_pd(r.y);
        float l = a1 + A2[(size_t)src * NHEADS + h] + pd.x * ch + pd.y;
        l = (l >= 0.f) ? l : LEAKY * l;
        float ex = __expf(l);
        s += ex;
        float2 vf = __half22float2(Vh2[(size_t)src * (DIM / 2) + d]);
        accx += ex * vf.x;
        accy += ex * vf.y;
    }
    float inv = 1.f / (s + 1e-12f);
    agg2[(size_t)n * (DIM / 2) + d] = make_float2(accx * inv, accy * inv);
}

// -- K7: out = agg@Wout^T + b + (H@res_w^T + res_b), LayerNorm ---------------
// 256 thr, 32 nodes/block; thread (dgrp=t&31, igrp=t>>5) owns 4 nodes x 4 dims
__global__ __launch_bounds__(256, 4) void k_out_ln(
    const float* __restrict__ agg, const float* __restrict__ H,
    const float* __restrict__ Wout, const float* __restrict__ bout,
    const float* __restrict__ Wres, const float* __restrict__ bres,
    const float* __restrict__ ln_g, const float* __restrict__ ln_b,
    float* __restrict__ out) {
    __shared__ __align__(16) float As[OPB][DIM + 4];
    __shared__ __align__(16) float Hs[OPB][DIM + 4];
    int t = threadIdx.x;
    int n0 = blockIdx.x * OPB;
    // cooperative load: 1024 float4 per matrix, 4 per thread, coalesced
    #pragma unroll
    for (int q = 0; q < 4; ++q) {
        int f = q * 256 + t;            // float4 index
        int row = f >> 5, c4 = f & 31;
        int nn = n0 + row;
        if (nn >= N_NODES) nn = N_NODES - 1;   // clamp (ws is valid memory)
        float4 av = *reinterpret_cast<const float4*>(&agg[(size_t)nn * DIM + c4 * 4]);
        float4 hv = *reinterpret_cast<const float4*>(&H[(size_t)nn * DIM + c4 * 4]);
        *reinterpret_cast<float4*>(&As[row][c4 * 4]) = av;
        *reinterpret_cast<float4*>(&Hs[row][c4 * 4]) = hv;
    }
    __syncthreads();
    int dgrp = t & 31;
    int i0 = (t >> 5) * 4;              // 4 nodes: i0..i0+3
    float acc[4][4];
    #pragma unroll
    for (int i = 0; i < 4; ++i)
        #pragma unroll
        for (int j = 0; j < 4; ++j) acc[i][j] = 0.f;
    const float4* Wo4 = reinterpret_cast<const float4*>(Wout);
    const float4* Wr4 = reinterpret_cast<const float4*>(Wres);
    for (int k4 = 0; k4 < DIM / 4; ++k4) {
        float4 wo[4], wr[4];
        #pragma unroll
        for (int j = 0; j < 4; ++j) {
            int dj = dgrp + 32 * j;
            wo[j] = Wo4[(size_t)dj * (DIM / 4) + k4];
            wr[j] = Wr4[(size_t)dj * (DIM / 4) + k4];
        }
        #pragma unroll
        for (int i = 0; i < 4; ++i) {
            float4 a = *reinterpret_cast<const float4*>(&As[i0 + i][k4 * 4]);
            float4 hh = *reinterpret_cast<const float4*>(&Hs[i0 + i][k4 * 4]);
            #pragma unroll
            for (int j = 0; j < 4; ++j) {
                acc[i][j] += a.x * wo[j].x + a.y * wo[j].y + a.z * wo[j].z + a.w * wo[j].w
                           + hh.x * wr[j].x + hh.y * wr[j].y + hh.z * wr[j].z + hh.w * wr[j].w;
            }
        }
    }
    // add biases
    #pragma unroll
    for (int j = 0; j < 4; ++j) {
        int dj = dgrp + 32 * j;
        float bo = bout[dj] + bres[dj];
        #pragma unroll
        for (int i = 0; i < 4; ++i) acc[i][j] += bo;
    }
    // LayerNorm: reduce sum/sumsq over the 32 lanes of this igrp group
    float sum[4], sq[4];
    #pragma unroll
    for (int i = 0; i < 4; ++i) {
        float s = 0.f, q = 0.f;
        #pragma unroll
        for (int j = 0; j < 4; ++j) { s += acc[i][j]; q += acc[i][j] * acc[i][j]; }
        sum[i] = s; sq[i] = q;
    }
    #pragma unroll
    for (int m = 1; m < 32; m <<= 1) {
        #pragma unroll
        for (int i = 0; i < 4; ++i) {
            sum[i] += __shfl_xor(sum[i], m, 64);
            sq[i]  += __shfl_xor(sq[i], m, 64);
        }
    }
    float mu[4], rs[4];
    #pragma unroll
    for (int i = 0; i < 4; ++i) {
        mu[i] = sum[i] * (1.f / DIM);
        float var = sq[i] * (1.f / DIM) - mu[i] * mu[i];
        rs[i] = rsqrtf(var + LN_EPS);
    }
    #pragma unroll
    for (int j = 0; j < 4; ++j) {
        int dj = dgrp + 32 * j;
        float g = ln_g[dj], b = ln_b[dj];
        #pragma unroll
        for (int i = 0; i < 4; ++i) {
            int n = n0 + i0 + i;
            if (n < N_NODES)
                out[(size_t)n * DIM + dj] = (acc[i][j] - mu[i]) * rs[i] * g + b;
        }
    }
}

// ---------------------------------------------------------------------------
extern "C" void kernel_launch(void* const* d_in, const int* in_sizes, int n_in,
                              void* d_out, int out_size, void* d_ws, size_t ws_size,
                              hipStream_t stream) {
    const float* H      = (const float*)d_in[0];
    const int*   ei     = (const int*)d_in[1];
    const float* P      = (const float*)d_in[2];
    const float* deter  = (const float*)d_in[3];
    const float* W1     = (const float*)d_in[4];
    const float* W2     = (const float*)d_in[5];
    const float* W3     = (const float*)d_in[6];
    const float* W4     = (const float*)d_in[7];
    const float* Wv     = (const float*)d_in[8];
    const float* Wout_w = (const float*)d_in[9];
    const float* Wout_b = (const float*)d_in[10];
    const float* res_w  = (const float*)d_in[11];
    const float* res_b  = (const float*)d_in[12];
    const float* ln_g   = (const float*)d_in[13];
    const float* ln_b   = (const float*)d_in[14];

    float* ws = (float*)d_ws;
    const size_t ND  = (size_t)N_NODES * DIM;      // 6,400,000
    const size_t NH8 = (size_t)N_NODES * NHEADS;   // 400,000

    __half* Vh  = (__half*)ws;            // ND halves = ND/2 floats
    float* agg  = ws + ND / 2;            // ND
    float* A1   = agg + ND;               // NH8
    float* A2   = A1 + NH8;               // NH8
    float* U1   = A2 + NH8;               // 1024
    float* U2   = U1 + NHEADS * DIM;      // 1024
    float* cvec = U2 + NHEADS * DIM;      // 16
    int2*  rec  = (int2*)(cvec + 16);     // E records (8B each)
    int* deg     = (int*)(rec + N_EDGES); // N
    int* row_off = deg + N_NODES;         // N+1
    int* cursor  = row_off + N_NODES + 1; // N
    int* partial = cursor + N_NODES;      // 256
    // total ~13.9M words (~56 MB)

    hipMemsetAsync(deg, 0, N_NODES * sizeof(int), stream);

    k_prep<<<NHEADS, DIM, 0, stream>>>(W1, W2, W3, W4, U1, U2, cvec);
    k_node_va<<<N_NODES / NPB, DIM, 0, stream>>>(H, Wv, U1, U2, Vh, A1, A2);
    k_hist<<<(N_EDGES + 255) / 256, 256, 0, stream>>>(ei, deg);
    k_scan1<<<NSB, 256, 0, stream>>>(deg, partial);
    k_scan3<<<NSB, 256, 0, stream>>>(deg, partial, row_off, cursor);
    k_bucket<<<(N_EDGES + 255) / 256, 256, 0, stream>>>(ei, P, deter, cursor, rec);
    k_sm_agg<<<(N_NODES + 3) / 4, 256, 0, stream>>>(row_off, rec, A1, A2, cvec,
                                                    (const __half2*)Vh, (float2*)agg);
    k_out_ln<<<(N_NODES + OPB - 1) / OPB, 256, 0, stream>>>(
        agg, H, Wout_w, Wout_b, res_w, res_b, ln_g, ln_b, (float*)d_out);
}

// Round 6
// 325.195 us; speedup vs baseline: 1.5499x; 1.5499x over previous
//
#include <hip/hip_runtime.h>
#include <hip/hip_fp16.h>
#include <math.h>

#define N_NODES 50000
#define N_EDGES 800000
#define DIM 128
#define NHEADS 8
#define LN_EPS 1e-5f
#define LEAKY 0.2f
#define NPB 16     // nodes per block for k_node_va
#define NSB 196    // ceil(N_NODES/256) scan blocks

typedef _Float16 half8 __attribute__((ext_vector_type(8)));
typedef float floatx4 __attribute__((ext_vector_type(4)));

// ---------------- pack/unpack (P, deter) as half2 in one int ----------------
__device__ __forceinline__ int pack_pd(float p, float dt) {
    __half2 h = __floats2half2_rn(p, dt);
    int r; __builtin_memcpy(&r, &h, 4); return r;
}
__device__ __forceinline__ float2 unpack_pd(int v) {
    __half2 h; __builtin_memcpy(&h, &v, 4);
    return __half22float2(h);   // .x = P, .y = deter
}

// ---------------- K1: U1 = W4@W1, U2 = W4@W2, c = W4@W3 (tiny) --------------
__global__ __launch_bounds__(128) void k_prep(
    const float* __restrict__ W1, const float* __restrict__ W2,
    const float* __restrict__ W3, const float* __restrict__ W4,
    float* __restrict__ U1, float* __restrict__ U2, float* __restrict__ c) {
    int h = blockIdx.x;       // 0..7
    int k = threadIdx.x;      // 0..127
    float a1 = 0.f, a2 = 0.f;
    for (int d = 0; d < DIM; ++d) {
        float w4 = W4[h * DIM + d];
        a1 += w4 * W1[d * DIM + k];
        a2 += w4 * W2[d * DIM + k];
    }
    U1[h * DIM + k] = a1;
    U2[h * DIM + k] = a2;
    __shared__ float red[DIM];
    red[k] = W4[h * DIM + k] * W3[k];
    __syncthreads();
    if (k == 0) {
        float s = 0.f;
        for (int i = 0; i < DIM; ++i) s += red[i];
        c[h] = s;
    }
}

// ------- K1b: Wch[d][0:128]=fp16(Wout[d]), [128:256]=fp16(res_w[d]); bsum ---
__global__ __launch_bounds__(256) void k_wcat(
    const float* __restrict__ Wout, const float* __restrict__ Wres,
    const float* __restrict__ bout, const float* __restrict__ bres,
    __half* __restrict__ Wch, float* __restrict__ bsum) {
    int d = blockIdx.x;     // 0..127
    int t = threadIdx.x;    // 0..255
    float v = (t < 128) ? Wout[d * 128 + t] : Wres[d * 128 + (t - 128)];
    Wch[(size_t)d * 256 + t] = __float2half_rn(v);
    if (d == 0 && t < 128) bsum[t] = bout[t] + bres[t];
}

// -- K2: Vh = fp16(H@Wv^T); Xh[:,128:256] = fp16(H); A1 = H@U1^T; A2 = H@U2^T
__global__ __launch_bounds__(128) void k_node_va(
    const float* __restrict__ H, const float* __restrict__ Wv,
    const float* __restrict__ U1, const float* __restrict__ U2,
    __half* __restrict__ Vh, __half* __restrict__ Xh,
    float* __restrict__ A1, float* __restrict__ A2) {
    __shared__ __align__(16) float Hs[NPB][DIM + 4];
    __shared__ float Us1[NHEADS * 130];
    __shared__ float Us2[NHEADS * 130];
    int d = threadIdx.x;
    int n0 = blockIdx.x * NPB;
    #pragma unroll
    for (int i = 0; i < NPB; ++i) Hs[i][d] = H[(size_t)(n0 + i) * DIM + d];
    #pragma unroll
    for (int r = 0; r < NHEADS; ++r) {
        Us1[r * 130 + d] = U1[r * DIM + d];
        Us2[r * 130 + d] = U2[r * DIM + d];
    }
    __syncthreads();
    float accv[NPB];
    #pragma unroll
    for (int i = 0; i < NPB; ++i) accv[i] = 0.f;
    const float4* Wv4 = reinterpret_cast<const float4*>(Wv + (size_t)d * DIM);
    #pragma unroll 4
    for (int k4 = 0; k4 < DIM / 4; ++k4) {
        float4 wv = Wv4[k4];
        #pragma unroll
        for (int i = 0; i < NPB; ++i) {
            float4 hh = *reinterpret_cast<const float4*>(&Hs[i][k4 * 4]);
            accv[i] += hh.x * wv.x + hh.y * wv.y + hh.z * wv.z + hh.w * wv.w;
        }
    }
    #pragma unroll
    for (int i = 0; i < NPB; ++i) {
        Vh[(size_t)(n0 + i) * DIM + d] = __float2half_rn(accv[i]);
        Xh[(size_t)(n0 + i) * 256 + 128 + d] = __float2half_rn(Hs[i][d]);
    }
    int i = d >> 3, h = d & 7;
    float a1 = 0.f, a2 = 0.f;
    for (int k = 0; k < DIM; ++k) {
        float hv = Hs[i][k];
        a1 += hv * Us1[h * 130 + k];
        a2 += hv * Us2[h * 130 + k];
    }
    A1[(size_t)(n0 + i) * NHEADS + h] = a1;   // coalesced: A1[n0*8 + d]
    A2[(size_t)(n0 + i) * NHEADS + h] = a2;
}

// ---------------- K3: degree histogram --------------------------------------
__global__ __launch_bounds__(256) void k_hist(
    const int* __restrict__ ei, int* __restrict__ deg) {
    int e = blockIdx.x * 256 + threadIdx.x;
    if (e < N_EDGES) atomicAdd(&deg[ei[N_EDGES + e]], 1);
}

// ---------------- K4a: per-block partial sums of deg ------------------------
__global__ __launch_bounds__(256) void k_scan1(
    const int* __restrict__ deg, int* __restrict__ partial) {
    int t = threadIdx.x;
    int idx = blockIdx.x * 256 + t;
    int v = (idx < N_NODES) ? deg[idx] : 0;
    #pragma unroll
    for (int off = 32; off > 0; off >>= 1) v += __shfl_down(v, off, 64);
    __shared__ int ws_[4];
    if ((t & 63) == 0) ws_[t >> 6] = v;
    __syncthreads();
    if (t == 0) partial[blockIdx.x] = ws_[0] + ws_[1] + ws_[2] + ws_[3];
}

// -------- K4b: per-block local scan; each block also scans the partials -----
__global__ __launch_bounds__(256) void k_scan3(
    const int* __restrict__ deg, const int* __restrict__ partial,
    int* __restrict__ row_off, int* __restrict__ cursor) {
    __shared__ int shp[256];
    __shared__ int sh[256];
    int t = threadIdx.x;
    int pv = (t < NSB) ? partial[t] : 0;
    shp[t] = pv;
    int idx = blockIdx.x * 256 + t;
    int v = (idx < N_NODES) ? deg[idx] : 0;
    sh[t] = v;
    __syncthreads();
    #pragma unroll
    for (int off = 1; off < 256; off <<= 1) {
        int u1 = (t >= off) ? shp[t - off] : 0;
        int u2 = (t >= off) ? sh[t - off] : 0;
        __syncthreads();
        shp[t] += u1;
        sh[t] += u2;
        __syncthreads();
    }
    int pofs = (blockIdx.x == 0) ? 0 : shp[blockIdx.x - 1];
    int excl = sh[t] - v + pofs;
    if (idx < N_NODES) {
        row_off[idx] = excl;
        cursor[idx] = excl;
    }
    if (idx == N_NODES - 1) row_off[N_NODES] = excl + v;   // == N_EDGES
}

// ---------------- K5: bucket edges by dst; record = (src, half2(P,deter)) ---
__global__ __launch_bounds__(256) void k_bucket(
    const int* __restrict__ ei, const float* __restrict__ P,
    const float* __restrict__ deter, int* __restrict__ cursor,
    int2* __restrict__ rec) {
    int e = blockIdx.x * 256 + threadIdx.x;
    if (e >= N_EDGES) return;
    int src = ei[e];
    int dst = ei[N_EDGES + e];
    int pos = atomicAdd(&cursor[dst], 1);
    rec[pos] = make_int2(src, pack_pd(P[e], deter[e]));
}

// ---------------- K6: fused softmax + aggregation (4x unrolled) -------------
// wave per node; lane d owns dims (2d, 2d+1) -> head h = d>>3
// writes fp16 result into Xh[n][0:128]
__global__ __launch_bounds__(256) void k_sm_agg(
    const int* __restrict__ row_off, const int2* __restrict__ rec,
    const float* __restrict__ A1, const float* __restrict__ A2,
    const float* __restrict__ cvec, const __half2* __restrict__ Vh2,
    __half* __restrict__ Xh) {
    int n = (blockIdx.x * 256 + threadIdx.x) >> 6;
    int d = threadIdx.x & 63;
    if (n >= N_NODES) return;
    int h = d >> 3;
    float a1 = A1[(size_t)n * NHEADS + h];
    float ch = cvec[h];
    int start = row_off[n], end = row_off[n + 1];
    float s = 0.f, accx = 0.f, accy = 0.f;
    int j = start;
    for (; j + 4 <= end; j += 4) {
        int2 r0 = rec[j], r1 = rec[j + 1], r2 = rec[j + 2], r3 = rec[j + 3];
        int s0 = r0.x, s1 = r1.x, s2 = r2.x, s3 = r3.x;
        float a20 = A2[(size_t)s0 * NHEADS + h];
        float a21 = A2[(size_t)s1 * NHEADS + h];
        float a22 = A2[(size_t)s2 * NHEADS + h];
        float a23 = A2[(size_t)s3 * NHEADS + h];
        __half2 v0 = Vh2[(size_t)s0 * (DIM / 2) + d];
        __half2 v1 = Vh2[(size_t)s1 * (DIM / 2) + d];
        __half2 v2 = Vh2[(size_t)s2 * (DIM / 2) + d];
        __half2 v3 = Vh2[(size_t)s3 * (DIM / 2) + d];
        float2 p0 = unpack_pd(r0.y), p1 = unpack_pd(r1.y);
        float2 p2 = unpack_pd(r2.y), p3 = unpack_pd(r3.y);
        float l0 = a1 + a20 + p0.x * ch + p0.y;
        float l1 = a1 + a21 + p1.x * ch + p1.y;
        float l2 = a1 + a22 + p2.x * ch + p2.y;
        float l3 = a1 + a23 + p3.x * ch + p3.y;
        l0 = (l0 >= 0.f) ? l0 : LEAKY * l0;
        l1 = (l1 >= 0.f) ? l1 : LEAKY * l1;
        l2 = (l2 >= 0.f) ? l2 : LEAKY * l2;
        l3 = (l3 >= 0.f) ? l3 : LEAKY * l3;
        float e0 = __expf(l0), e1 = __expf(l1), e2 = __expf(l2), e3 = __expf(l3);
        s += e0 + e1 + e2 + e3;
        float2 f0 = __half22float2(v0), f1 = __half22float2(v1);
        float2 f2 = __half22float2(v2), f3 = __half22float2(v3);
        accx += e0 * f0.x + e1 * f1.x + e2 * f2.x + e3 * f3.x;
        accy += e0 * f0.y + e1 * f1.y + e2 * f2.y + e3 * f3.y;
    }
    for (; j < end; ++j) {
        int2 r = rec[j];
        int src = r.x;
        float2 pd = unpack_pd(r.y);
        float l = a1 + A2[(size_t)src * NHEADS + h] + pd.x * ch + pd.y;
        l = (l >= 0.f) ? l : LEAKY * l;
        float ex = __expf(l);
        s += ex;
        float2 vf = __half22float2(Vh2[(size_t)src * (DIM / 2) + d]);
        accx += ex * vf.x;
        accy += ex * vf.y;
    }
    float inv = 1.f / (s + 1e-12f);
    __half2 o = __floats2half2_rn(accx * inv, accy * inv);
    *reinterpret_cast<__half2*>(Xh + (size_t)n * 256 + 2 * d) = o;
}

// -- K7: out = Xh(N,256) @ Wch(128,256)^T + bsum, LayerNorm — MFMA -----------
// one wave per 32 nodes; 2 row-tiles x 8 col-tiles of 16x16x32 f16 MFMA
__global__ __launch_bounds__(64) void k_out_mfma(
    const __half* __restrict__ Xh_, const __half* __restrict__ Wch_,
    const float* __restrict__ bsum, const float* __restrict__ ln_g,
    const float* __restrict__ ln_b, float* __restrict__ out) {
    const _Float16* Xh = reinterpret_cast<const _Float16*>(Xh_);
    const _Float16* Wch = reinterpret_cast<const _Float16*>(Wch_);
    int lane = threadIdx.x;          // 0..63
    int m = lane & 15, q = lane >> 4;
    int n0 = blockIdx.x * 32;
    floatx4 z = {0.f, 0.f, 0.f, 0.f};
    floatx4 acc[2][8];
    #pragma unroll
    for (int t = 0; t < 2; ++t)
        #pragma unroll
        for (int j = 0; j < 8; ++j) acc[t][j] = z;
    int r0 = n0 + m;        if (r0 >= N_NODES) r0 = N_NODES - 1;
    int r1 = n0 + 16 + m;   if (r1 >= N_NODES) r1 = N_NODES - 1;
    const _Float16* X0 = Xh + (size_t)r0 * 256 + q * 8;
    const _Float16* X1 = Xh + (size_t)r1 * 256 + q * 8;
    const _Float16* Wb = Wch + (size_t)m * 256 + q * 8;
    #pragma unroll
    for (int ks = 0; ks < 8; ++ks) {
        half8 a0 = *reinterpret_cast<const half8*>(X0 + ks * 32);
        half8 a1 = *reinterpret_cast<const half8*>(X1 + ks * 32);
        #pragma unroll
        for (int j = 0; j < 8; ++j) {
            half8 b = *reinterpret_cast<const half8*>(Wb + (size_t)j * 16 * 256 + ks * 32);
            acc[0][j] = __builtin_amdgcn_mfma_f32_16x16x32_f16(a0, b, acc[0][j], 0, 0, 0);
            acc[1][j] = __builtin_amdgcn_mfma_f32_16x16x32_f16(a1, b, acc[1][j], 0, 0, 0);
        }
    }
    float bsv[8], gv[8], bv[8];
    #pragma unroll
    for (int j = 0; j < 8; ++j) {
        bsv[j] = bsum[j * 16 + m];
        gv[j]  = ln_g[j * 16 + m];
        bv[j]  = ln_b[j * 16 + m];
    }
    // C/D layout: col = lane&15 (=m), row = q*4 + reg
    #pragma unroll
    for (int t = 0; t < 2; ++t) {
        #pragma unroll
        for (int reg = 0; reg < 4; ++reg) {
            float v[8];
            float s = 0.f, sq = 0.f;
            #pragma unroll
            for (int j = 0; j < 8; ++j) {
                v[j] = acc[t][j][reg] + bsv[j];
                s += v[j];
                sq += v[j] * v[j];
            }
            #pragma unroll
            for (int mk = 1; mk < 16; mk <<= 1) {
                s  += __shfl_xor(s, mk, 64);
                sq += __shfl_xor(sq, mk, 64);
            }
            float mu = s * (1.f / DIM);
            float var = sq * (1.f / DIM) - mu * mu;
            float rs = rsqrtf(var + LN_EPS);
            int n = n0 + t * 16 + q * 4 + reg;
            if (n < N_NODES) {
                #pragma unroll
                for (int j = 0; j < 8; ++j)
                    out[(size_t)n * DIM + j * 16 + m] = (v[j] - mu) * rs * gv[j] + bv[j];
            }
        }
    }
}

// ---------------------------------------------------------------------------
extern "C" void kernel_launch(void* const* d_in, const int* in_sizes, int n_in,
                              void* d_out, int out_size, void* d_ws, size_t ws_size,
                              hipStream_t stream) {
    const float* H      = (const float*)d_in[0];
    const int*   ei     = (const int*)d_in[1];
    const float* P      = (const float*)d_in[2];
    const float* deter  = (const float*)d_in[3];
    const float* W1     = (const float*)d_in[4];
    const float* W2     = (const float*)d_in[5];
    const float* W3     = (const float*)d_in[6];
    const float* W4     = (const float*)d_in[7];
    const float* Wv     = (const float*)d_in[8];
    const float* Wout_w = (const float*)d_in[9];
    const float* Wout_b = (const float*)d_in[10];
    const float* res_w  = (const float*)d_in[11];
    const float* res_b  = (const float*)d_in[12];
    const float* ln_g   = (const float*)d_in[13];
    const float* ln_b   = (const float*)d_in[14];

    float* ws = (float*)d_ws;
    const size_t ND  = (size_t)N_NODES * DIM;      // 6,400,000
    const size_t NH8 = (size_t)N_NODES * NHEADS;   // 400,000

    __half* Xh  = (__half*)ws;            // N*256 halves = ND floats of space /2? (N*128 float words)
    float* fbase = ws + (size_t)N_NODES * 128;   // after Xh (N*256 halves = N*128 words)
    __half* Vh  = (__half*)fbase;         // N*128 halves = N*64 words
    float* A1   = fbase + (size_t)N_NODES * 64;  // NH8
    float* A2   = A1 + NH8;               // NH8
    float* U1   = A2 + NH8;               // 1024
    float* U2   = U1 + NHEADS * DIM;      // 1024
    float* cvec = U2 + NHEADS * DIM;      // 16
    float* bsum = cvec + 16;              // 128
    __half* Wch = (__half*)(bsum + 128);  // 128*256 halves = 16384 words
    int2*  rec  = (int2*)(Wch + 128 * 256);  // E records (8B each)
    int* deg     = (int*)(rec + N_EDGES); // N
    int* row_off = deg + N_NODES;         // N+1
    int* cursor  = row_off + N_NODES + 1; // N
    int* partial = cursor + N_NODES;      // 256
    // total ~12.2M words (~49 MB)

    hipMemsetAsync(deg, 0, N_NODES * sizeof(int), stream);

    k_prep<<<NHEADS, DIM, 0, stream>>>(W1, W2, W3, W4, U1, U2, cvec);
    k_wcat<<<DIM, 256, 0, stream>>>(Wout_w, res_w, Wout_b, res_b, Wch, bsum);
    k_node_va<<<N_NODES / NPB, DIM, 0, stream>>>(H, Wv, U1, U2, Vh, Xh, A1, A2);
    k_hist<<<(N_EDGES + 255) / 256, 256, 0, stream>>>(ei, deg);
    k_scan1<<<NSB, 256, 0, stream>>>(deg, partial);
    k_scan3<<<NSB, 256, 0, stream>>>(deg, partial, row_off, cursor);
    k_bucket<<<(N_EDGES + 255) / 256, 256, 0, stream>>>(ei, P, deter, cursor, rec);
    k_sm_agg<<<(N_NODES + 3) / 4, 256, 0, stream>>>(row_off, rec, A1, A2, cvec,
                                                    (const __half2*)Vh, Xh);
    k_out_mfma<<<(N_NODES + 31) / 32, 64, 0, stream>>>(Xh, Wch, bsum, ln_g, ln_b,
                                                       (float*)d_out);
}

// Round 7
// 293.670 us; speedup vs baseline: 1.7163x; 1.1073x over previous
//
#include <hip/hip_runtime.h>
#include <hip/hip_fp16.h>
#include <math.h>

#define N_NODES 50000
#define N_EDGES 800000
#define DIM 128
#define NHEADS 8
#define LN_EPS 1e-5f
#define LEAKY 0.2f
#define NSB 196    // ceil(N_NODES/256) scan blocks

typedef _Float16 half8 __attribute__((ext_vector_type(8)));
typedef float floatx4 __attribute__((ext_vector_type(4)));

// ---------------- pack/unpack (P, deter) as half2 in one int ----------------
__device__ __forceinline__ int pack_pd(float p, float dt) {
    __half2 h = __floats2half2_rn(p, dt);
    int r; __builtin_memcpy(&r, &h, 4); return r;
}
__device__ __forceinline__ float2 unpack_pd(int v) {
    __half2 h; __builtin_memcpy(&h, &v, 4);
    return __half22float2(h);   // .x = P, .y = deter
}

// ------ K1: Wcat rows 128..135 = fp16(W4@W1), 136..143 = fp16(W4@W2); c -----
__global__ __launch_bounds__(128) void k_prep(
    const float* __restrict__ W1, const float* __restrict__ W2,
    const float* __restrict__ W3, const float* __restrict__ W4,
    __half* __restrict__ Wcat, float* __restrict__ c) {
    int h = blockIdx.x;       // 0..7
    int k = threadIdx.x;      // 0..127
    float a1 = 0.f, a2 = 0.f;
    for (int d = 0; d < DIM; ++d) {
        float w4 = W4[h * DIM + d];
        a1 += w4 * W1[d * DIM + k];
        a2 += w4 * W2[d * DIM + k];
    }
    Wcat[(size_t)(128 + h) * DIM + k] = __float2half_rn(a1);
    Wcat[(size_t)(136 + h) * DIM + k] = __float2half_rn(a2);
    __shared__ float red[DIM];
    red[k] = W4[h * DIM + k] * W3[k];
    __syncthreads();
    if (k == 0) {
        float s = 0.f;
        for (int i = 0; i < DIM; ++i) s += red[i];
        c[h] = s;
    }
}

// -- K1b: Wch = fp16[Wout|res_w] (128x256); Wcat rows 0..127 = fp16(Wv); bsum
__global__ __launch_bounds__(256) void k_wcat(
    const float* __restrict__ Wout, const float* __restrict__ Wres,
    const float* __restrict__ Wv, const float* __restrict__ bout,
    const float* __restrict__ bres, __half* __restrict__ Wch,
    __half* __restrict__ Wcat, float* __restrict__ bsum) {
    int d = blockIdx.x;     // 0..127
    int t = threadIdx.x;    // 0..255
    float v = (t < 128) ? Wout[d * 128 + t] : Wres[d * 128 + (t - 128)];
    Wch[(size_t)d * 256 + t] = __float2half_rn(v);
    if (t < 128) Wcat[(size_t)d * DIM + t] = __float2half_rn(Wv[d * 128 + t]);
    if (d == 0 && t < 128) bsum[t] = bout[t] + bres[t];
}

// -- K2: MFMA  Y = H @ Wcat^T  (M=N_NODES, N=144, K=128, fp16 in / fp32 acc) -
//   cols 0..127 -> Vh (fp16), cols 128..135 -> A1, 136..143 -> A2 (fp32)
//   side effect: Xh[:,128:256] = fp16(H)  (converted A-fragments)
__global__ __launch_bounds__(64) void k_node_mfma(
    const float* __restrict__ H, const __half* __restrict__ Wcat_,
    __half* __restrict__ Vh, __half* __restrict__ Xh,
    float* __restrict__ A1, float* __restrict__ A2) {
    const _Float16* Wcat = reinterpret_cast<const _Float16*>(Wcat_);
    int lane = threadIdx.x;          // 0..63
    int m = lane & 15, q = lane >> 4;
    int n0 = blockIdx.x * 32;
    floatx4 z = {0.f, 0.f, 0.f, 0.f};
    floatx4 acc[2][9];
    #pragma unroll
    for (int t = 0; t < 2; ++t)
        #pragma unroll
        for (int j = 0; j < 9; ++j) acc[t][j] = z;
    int r0 = n0 + m;        if (r0 >= N_NODES) r0 = N_NODES - 1;
    int r1 = n0 + 16 + m;   if (r1 >= N_NODES) r1 = N_NODES - 1;
    const float* H0 = H + (size_t)r0 * DIM + q * 8;
    const float* H1 = H + (size_t)r1 * DIM + q * 8;
    _Float16* Xw0 = reinterpret_cast<_Float16*>(Xh) + (size_t)r0 * 256 + 128 + q * 8;
    _Float16* Xw1 = reinterpret_cast<_Float16*>(Xh) + (size_t)r1 * 256 + 128 + q * 8;
    const _Float16* Wb = Wcat + (size_t)m * DIM + q * 8;
    #pragma unroll
    for (int ks = 0; ks < 4; ++ks) {
        float4 fa = *reinterpret_cast<const float4*>(H0 + ks * 32);
        float4 fb = *reinterpret_cast<const float4*>(H0 + ks * 32 + 4);
        float4 ga = *reinterpret_cast<const float4*>(H1 + ks * 32);
        float4 gb = *reinterpret_cast<const float4*>(H1 + ks * 32 + 4);
        half8 a0, a1v;
        a0[0] = (_Float16)fa.x; a0[1] = (_Float16)fa.y;
        a0[2] = (_Float16)fa.z; a0[3] = (_Float16)fa.w;
        a0[4] = (_Float16)fb.x; a0[5] = (_Float16)fb.y;
        a0[6] = (_Float16)fb.z; a0[7] = (_Float16)fb.w;
        a1v[0] = (_Float16)ga.x; a1v[1] = (_Float16)ga.y;
        a1v[2] = (_Float16)ga.z; a1v[3] = (_Float16)ga.w;
        a1v[4] = (_Float16)gb.x; a1v[5] = (_Float16)gb.y;
        a1v[6] = (_Float16)gb.z; a1v[7] = (_Float16)gb.w;
        *reinterpret_cast<half8*>(Xw0 + ks * 32) = a0;
        *reinterpret_cast<half8*>(Xw1 + ks * 32) = a1v;
        #pragma unroll
        for (int j = 0; j < 9; ++j) {
            half8 b = *reinterpret_cast<const half8*>(Wb + (size_t)j * 16 * DIM + ks * 32);
            acc[0][j] = __builtin_amdgcn_mfma_f32_16x16x32_f16(a0, b, acc[0][j], 0, 0, 0);
            acc[1][j] = __builtin_amdgcn_mfma_f32_16x16x32_f16(a1v, b, acc[1][j], 0, 0, 0);
        }
    }
    // C/D layout: col = m, row = q*4 + reg (within 16-row tile)
    #pragma unroll
    for (int t = 0; t < 2; ++t) {
        #pragma unroll
        for (int reg = 0; reg < 4; ++reg) {
            int n = n0 + t * 16 + q * 4 + reg;
            if (n < N_NODES) {
                #pragma unroll
                for (int j = 0; j < 8; ++j)
                    Vh[(size_t)n * DIM + j * 16 + m] = __float2half_rn(acc[t][j][reg]);
                float av = acc[t][8][reg];
                if (m < 8) A1[(size_t)n * NHEADS + m] = av;
                else       A2[(size_t)n * NHEADS + (m - 8)] = av;
            }
        }
    }
}

// ---------------- K3: degree histogram --------------------------------------
__global__ __launch_bounds__(256) void k_hist(
    const int* __restrict__ ei, int* __restrict__ deg) {
    int e = blockIdx.x * 256 + threadIdx.x;
    if (e < N_EDGES) atomicAdd(&deg[ei[N_EDGES + e]], 1);
}

// ---------------- K4a: per-block partial sums of deg ------------------------
__global__ __launch_bounds__(256) void k_scan1(
    const int* __restrict__ deg, int* __restrict__ partial) {
    int t = threadIdx.x;
    int idx = blockIdx.x * 256 + t;
    int v = (idx < N_NODES) ? deg[idx] : 0;
    #pragma unroll
    for (int off = 32; off > 0; off >>= 1) v += __shfl_down(v, off, 64);
    __shared__ int ws_[4];
    if ((t & 63) == 0) ws_[t >> 6] = v;
    __syncthreads();
    if (t == 0) partial[blockIdx.x] = ws_[0] + ws_[1] + ws_[2] + ws_[3];
}

// -------- K4b: per-block local scan; each block also scans the partials -----
__global__ __launch_bounds__(256) void k_scan3(
    const int* __restrict__ deg, const int* __restrict__ partial,
    int* __restrict__ row_off, int* __restrict__ cursor) {
    __shared__ int shp[256];
    __shared__ int sh[256];
    int t = threadIdx.x;
    int pv = (t < NSB) ? partial[t] : 0;
    shp[t] = pv;
    int idx = blockIdx.x * 256 + t;
    int v = (idx < N_NODES) ? deg[idx] : 0;
    sh[t] = v;
    __syncthreads();
    #pragma unroll
    for (int off = 1; off < 256; off <<= 1) {
        int u1 = (t >= off) ? shp[t - off] : 0;
        int u2 = (t >= off) ? sh[t - off] : 0;
        __syncthreads();
        shp[t] += u1;
        sh[t] += u2;
        __syncthreads();
    }
    int pofs = (blockIdx.x == 0) ? 0 : shp[blockIdx.x - 1];
    int excl = sh[t] - v + pofs;
    if (idx < N_NODES) {
        row_off[idx] = excl;
        cursor[idx] = excl;
    }
    if (idx == N_NODES - 1) row_off[N_NODES] = excl + v;   // == N_EDGES
}

// ---------------- K5: bucket edges by dst; record = (src, half2(P,deter)) ---
__global__ __launch_bounds__(256) void k_bucket(
    const int* __restrict__ ei, const float* __restrict__ P,
    const float* __restrict__ deter, int* __restrict__ cursor,
    int2* __restrict__ rec) {
    int e = blockIdx.x * 256 + threadIdx.x;
    if (e >= N_EDGES) return;
    int src = ei[e];
    int dst = ei[N_EDGES + e];
    int pos = atomicAdd(&cursor[dst], 1);
    rec[pos] = make_int2(src, pack_pd(P[e], deter[e]));
}

// ---------------- K6: fused softmax + aggregation (4x unrolled) -------------
// wave per node; lane d owns dims (2d, 2d+1) -> head h = d>>3
// writes fp16 result into Xh[n][0:128]
__global__ __launch_bounds__(256) void k_sm_agg(
    const int* __restrict__ row_off, const int2* __restrict__ rec,
    const float* __restrict__ A1, const float* __restrict__ A2,
    const float* __restrict__ cvec, const __half2* __restrict__ Vh2,
    __half* __restrict__ Xh) {
    int n = (blockIdx.x * 256 + threadIdx.x) >> 6;
    int d = threadIdx.x & 63;
    if (n >= N_NODES) return;
    int h = d >> 3;
    float a1 = A1[(size_t)n * NHEADS + h];
    float ch = cvec[h];
    int start = row_off[n], end = row_off[n + 1];
    float s = 0.f, accx = 0.f, accy = 0.f;
    int j = start;
    for (; j + 4 <= end; j += 4) {
        int2 r0 = rec[j], r1 = rec[j + 1], r2 = rec[j + 2], r3 = rec[j + 3];
        int s0 = r0.x, s1 = r1.x, s2 = r2.x, s3 = r3.x;
        float a20 = A2[(size_t)s0 * NHEADS + h];
        float a21 = A2[(size_t)s1 * NHEADS + h];
        float a22 = A2[(size_t)s2 * NHEADS + h];
        float a23 = A2[(size_t)s3 * NHEADS + h];
        __half2 v0 = Vh2[(size_t)s0 * (DIM / 2) + d];
        __half2 v1 = Vh2[(size_t)s1 * (DIM / 2) + d];
        __half2 v2 = Vh2[(size_t)s2 * (DIM / 2) + d];
        __half2 v3 = Vh2[(size_t)s3 * (DIM / 2) + d];
        float2 p0 = unpack_pd(r0.y), p1 = unpack_pd(r1.y);
        float2 p2 = unpack_pd(r2.y), p3 = unpack_pd(r3.y);
        float l0 = a1 + a20 + p0.x * ch + p0.y;
        float l1 = a1 + a21 + p1.x * ch + p1.y;
        float l2 = a1 + a22 + p2.x * ch + p2.y;
        float l3 = a1 + a23 + p3.x * ch + p3.y;
        l0 = (l0 >= 0.f) ? l0 : LEAKY * l0;
        l1 = (l1 >= 0.f) ? l1 : LEAKY * l1;
        l2 = (l2 >= 0.f) ? l2 : LEAKY * l2;
        l3 = (l3 >= 0.f) ? l3 : LEAKY * l3;
        float e0 = __expf(l0), e1 = __expf(l1), e2 = __expf(l2), e3 = __expf(l3);
        s += e0 + e1 + e2 + e3;
        float2 f0 = __half22float2(v0), f1 = __half22float2(v1);
        float2 f2 = __half22float2(v2), f3 = __half22float2(v3);
        accx += e0 * f0.x + e1 * f1.x + e2 * f2.x + e3 * f3.x;
        accy += e0 * f0.y + e1 * f1.y + e2 * f2.y + e3 * f3.y;
    }
    for (; j < end; ++j) {
        int2 r = rec[j];
        int src = r.x;
        float2 pd = unpack_pd(r.y);
        float l = a1 + A2[(size_t)src * NHEADS + h] + pd.x * ch + pd.y;
        l = (l >= 0.f) ? l : LEAKY * l;
        float ex = __expf(l);
        s += ex;
        float2 vf = __half22float2(Vh2[(size_t)src * (DIM / 2) + d]);
        accx += ex * vf.x;
        accy += ex * vf.y;
    }
    float inv = 1.f / (s + 1e-12f);
    __half2 o = __floats2half2_rn(accx * inv, accy * inv);
    *reinterpret_cast<__half2*>(Xh + (size_t)n * 256 + 2 * d) = o;
}

// -- K7: out = Xh(N,256) @ Wch(128,256)^T + bsum, LayerNorm — MFMA -----------
__global__ __launch_bounds__(64) void k_out_mfma(
    const __half* __restrict__ Xh_, const __half* __restrict__ Wch_,
    const float* __restrict__ bsum, const float* __restrict__ ln_g,
    const float* __restrict__ ln_b, float* __restrict__ out) {
    const _Float16* Xh = reinterpret_cast<const _Float16*>(Xh_);
    const _Float16* Wch = reinterpret_cast<const _Float16*>(Wch_);
    int lane = threadIdx.x;          // 0..63
    int m = lane & 15, q = lane >> 4;
    int n0 = blockIdx.x * 32;
    floatx4 z = {0.f, 0.f, 0.f, 0.f};
    floatx4 acc[2][8];
    #pragma unroll
    for (int t = 0; t < 2; ++t)
        #pragma unroll
        for (int j = 0; j < 8; ++j) acc[t][j] = z;
    int r0 = n0 + m;        if (r0 >= N_NODES) r0 = N_NODES - 1;
    int r1 = n0 + 16 + m;   if (r1 >= N_NODES) r1 = N_NODES - 1;
    const _Float16* X0 = Xh + (size_t)r0 * 256 + q * 8;
    const _Float16* X1 = Xh + (size_t)r1 * 256 + q * 8;
    const _Float16* Wb = Wch + (size_t)m * 256 + q * 8;
    #pragma unroll
    for (int ks = 0; ks < 8; ++ks) {
        half8 a0 = *reinterpret_cast<const half8*>(X0 + ks * 32);
        half8 a1 = *reinterpret_cast<const half8*>(X1 + ks * 32);
        #pragma unroll
        for (int j = 0; j < 8; ++j) {
            half8 b = *reinterpret_cast<const half8*>(Wb + (size_t)j * 16 * 256 + ks * 32);
            acc[0][j] = __builtin_amdgcn_mfma_f32_16x16x32_f16(a0, b, acc[0][j], 0, 0, 0);
            acc[1][j] = __builtin_amdgcn_mfma_f32_16x16x32_f16(a1, b, acc[1][j], 0, 0, 0);
        }
    }
    float bsv[8], gv[8], bv[8];
    #pragma unroll
    for (int j = 0; j < 8; ++j) {
        bsv[j] = bsum[j * 16 + m];
        gv[j]  = ln_g[j * 16 + m];
        bv[j]  = ln_b[j * 16 + m];
    }
    #pragma unroll
    for (int t = 0; t < 2; ++t) {
        #pragma unroll
        for (int reg = 0; reg < 4; ++reg) {
            float v[8];
            float s = 0.f, sq = 0.f;
            #pragma unroll
            for (int j = 0; j < 8; ++j) {
                v[j] = acc[t][j][reg] + bsv[j];
                s += v[j];
                sq += v[j] * v[j];
            }
            #pragma unroll
            for (int mk = 1; mk < 16; mk <<= 1) {
                s  += __shfl_xor(s, mk, 64);
                sq += __shfl_xor(sq, mk, 64);
            }
            float mu = s * (1.f / DIM);
            float var = sq * (1.f / DIM) - mu * mu;
            float rs = rsqrtf(var + LN_EPS);
            int n = n0 + t * 16 + q * 4 + reg;
            if (n < N_NODES) {
                #pragma unroll
                for (int j = 0; j < 8; ++j)
                    out[(size_t)n * DIM + j * 16 + m] = (v[j] - mu) * rs * gv[j] + bv[j];
            }
        }
    }
}

// ---------------------------------------------------------------------------
extern "C" void kernel_launch(void* const* d_in, const int* in_sizes, int n_in,
                              void* d_out, int out_size, void* d_ws, size_t ws_size,
                              hipStream_t stream) {
    const float* H      = (const float*)d_in[0];
    const int*   ei     = (const int*)d_in[1];
    const float* P      = (const float*)d_in[2];
    const float* deter  = (const float*)d_in[3];
    const float* W1     = (const float*)d_in[4];
    const float* W2     = (const float*)d_in[5];
    const float* W3     = (const float*)d_in[6];
    const float* W4     = (const float*)d_in[7];
    const float* Wv     = (const float*)d_in[8];
    const float* Wout_w = (const float*)d_in[9];
    const float* Wout_b = (const float*)d_in[10];
    const float* res_w  = (const float*)d_in[11];
    const float* res_b  = (const float*)d_in[12];
    const float* ln_g   = (const float*)d_in[13];
    const float* ln_b   = (const float*)d_in[14];

    float* ws = (float*)d_ws;
    const size_t NH8 = (size_t)N_NODES * NHEADS;   // 400,000

    __half* Xh  = (__half*)ws;                       // N*256 halves = N*128 words
    float* fbase = ws + (size_t)N_NODES * 128;
    __half* Vh  = (__half*)fbase;                    // N*128 halves = N*64 words
    float* A1   = fbase + (size_t)N_NODES * 64;      // NH8
    float* A2   = A1 + NH8;                          // NH8
    float* cvec = A2 + NH8;                          // 16
    float* bsum = cvec + 16;                         // 128
    __half* Wch  = (__half*)(bsum + 128);            // 128*256 halves = 16384 words
    __half* Wcat = Wch + 128 * 256;                  // 144*128 halves = 9216 words
    int2*  rec  = (int2*)(Wcat + 144 * 128);         // E records (8B each)
    int* deg     = (int*)(rec + N_EDGES);            // N
    int* row_off = deg + N_NODES;                    // N+1
    int* cursor  = row_off + N_NODES + 1;            // N
    int* partial = cursor + N_NODES;                 // 256
    // total ~12.2M words (~49 MB)

    hipMemsetAsync(deg, 0, N_NODES * sizeof(int), stream);

    k_prep<<<NHEADS, DIM, 0, stream>>>(W1, W2, W3, W4, Wcat, cvec);
    k_wcat<<<DIM, 256, 0, stream>>>(Wout_w, res_w, Wv, Wout_b, res_b, Wch, Wcat, bsum);
    k_node_mfma<<<(N_NODES + 31) / 32, 64, 0, stream>>>(H, Wcat, Vh, Xh, A1, A2);
    k_hist<<<(N_EDGES + 255) / 256, 256, 0, stream>>>(ei, deg);
    k_scan1<<<NSB, 256, 0, stream>>>(deg, partial);
    k_scan3<<<NSB, 256, 0, stream>>>(deg, partial, row_off, cursor);
    k_bucket<<<(N_EDGES + 255) / 256, 256, 0, stream>>>(ei, P, deter, cursor, rec);
    k_sm_agg<<<(N_NODES + 3) / 4, 256, 0, stream>>>(row_off, rec, A1, A2, cvec,
                                                    (const __half2*)Vh, Xh);
    k_out_mfma<<<(N_NODES + 31) / 32, 64, 0, stream>>>(Xh, Wch, bsum, ln_g, ln_b,
                                                       (float*)d_out);
}